// Round 11
// baseline (370.029 us; speedup 1.0000x reference)
//
#include <hip/hip_runtime.h>

#define ALPHA 0.01f
#define BIN_SHIFT 10
#define SBIN 1024            // buckets per bin
#define CAPB 8192            // fixed edge capacity per bin window (avg load ~3.3K)

typedef __attribute__((ext_vector_type(8))) short short8v;   // 8 x bf16 bits (4 VGPR)
typedef __attribute__((ext_vector_type(4))) float float4v;   // MFMA acc

// split fp32 -> bf16 hi + bf16 lo (truncation; residual capture => ~2^-24 total rel err)
__device__ __forceinline__ void bsplit(float x, unsigned short& hi, unsigned short& lo) {
  unsigned u = __float_as_uint(x);
  hi = (unsigned short)(u >> 16);
  float r = x - __uint_as_float(u & 0xFFFF0000u);
  lo = (unsigned short)(__float_as_uint(r) >> 16);
}

__device__ __forceinline__ void frag_from8(const float* v, short8v& hi, short8v& lo) {
#pragma unroll
  for (int e = 0; e < 8; ++e) {
    unsigned short h, l;
    bsplit(v[e], h, l);
    hi[e] = (short)h;
    lo[e] = (short)l;
  }
}

// ---------------- fused MFMA for ALL ntypes: G = relu(X @ W^T + b) @ Wo^T -------------
// (round-8 validated form: pad-17 hbuf, no prefetch — 73 us, VGPR 112)
__global__ __launch_bounds__(256, 2) void fused_mfma3_kernel(
    const float* __restrict__ Xu, const float* __restrict__ Xm, const float* __restrict__ Xd,
    const float* __restrict__ Wu, const float* __restrict__ Wm, const float* __restrict__ Wd,
    const float* __restrict__ Bu, const float* __restrict__ Bm, const float* __restrict__ Bd,
    const float* __restrict__ Wo,
    float* __restrict__ Gu, float* __restrict__ Gm, float* __restrict__ Gd,
    int NU, int NM, int ND, int bu, int bm)
{
  __shared__ char smem[65536 + 10368] __attribute__((aligned(16)));
  unsigned short* Whi = (unsigned short*)smem;
  unsigned short* Wlo = (unsigned short*)(smem + 32768);
  unsigned short* WoHi = (unsigned short*)(smem + 65536);
  unsigned short* WoLo = (unsigned short*)(smem + 65536 + 4096);

  const float *X, *W, *B;
  float* G;
  int N, bid, nbk;
  if ((int)blockIdx.x < bu)            { X = Xu; W = Wu; B = Bu; G = Gu; N = NU; bid = blockIdx.x;            nbk = bu; }
  else if ((int)blockIdx.x < bu + bm)  { X = Xm; W = Wm; B = Bm; G = Gm; N = NM; bid = blockIdx.x - bu;       nbk = bm; }
  else                                 { X = Xd; W = Wd; B = Bd; G = Gd; N = ND; bid = blockIdx.x - bu - bm;  nbk = gridDim.x - bu - bm; }

  const int t = threadIdx.x;
  const int wave = t >> 6;
  const int lane = t & 63;
  const int s = lane & 15;
  const int q = lane >> 4;
  float* hbuf = (float*)(smem + 65536 + wave * 2176);  // [32][17] f32, per-wave

#pragma unroll
  for (int i = 0; i < 32; ++i) {
    int p = i * 256 + t;
    int row = p >> 6, c2 = p & 63;
    float w0 = W[row * 128 + c2 * 2];
    float w1 = W[row * 128 + c2 * 2 + 1];
    unsigned short h0, l0, h1, l1;
    bsplit(w0, h0, l0); bsplit(w1, h1, l1);
    int u32idx = row * 64 + ((((c2 * 4) ^ ((row & 7) << 4))) >> 2);
    ((unsigned*)Whi)[u32idx] = (unsigned)h0 | ((unsigned)h1 << 16);
    ((unsigned*)Wlo)[u32idx] = (unsigned)l0 | ((unsigned)l1 << 16);
  }
#pragma unroll
  for (int i = 0; i < 4; ++i) {
    int p = i * 256 + t;
    int row = p >> 6, c2 = p & 63;
    float w0 = Wo[row * 128 + c2 * 2];
    float w1 = Wo[row * 128 + c2 * 2 + 1];
    unsigned short h0, l0, h1, l1;
    bsplit(w0, h0, l0); bsplit(w1, h1, l1);
    int u32idx = row * 64 + ((((c2 * 4) ^ ((row & 7) << 4))) >> 2);
    ((unsigned*)WoHi)[u32idx] = (unsigned)h0 | ((unsigned)h1 << 16);
    ((unsigned*)WoLo)[u32idx] = (unsigned)l0 | ((unsigned)l1 << 16);
  }
  __syncthreads();

  short8v woh[4], wol[4];
  const int woswz = (s & 7) << 4;
#pragma unroll
  for (int ks = 0; ks < 4; ++ks) {
    int off = s * 256 + ((ks * 64 + q * 16) ^ woswz);
    woh[ks] = *(const short8v*)((char*)WoHi + off);
    wol[ks] = *(const short8v*)((char*)WoLo + off);
  }
  float bv[8];
#pragma unroll
  for (int nt = 0; nt < 8; ++nt) bv[nt] = B[nt * 16 + s];
  __syncthreads();  // Wo staging area now reusable as hbuf

  const int nchunks = (N + 127) >> 7;
  const int bswz = (s & 7) << 4;

  for (int chunk = bid; chunk < nchunks; chunk += nbk) {
    const int rowbase = chunk * 128 + wave * 32;

    short8v ahi[2][4], alo[2][4];
#pragma unroll
    for (int mt = 0; mt < 2; ++mt) {
      int row = rowbase + mt * 16 + s;
      int crow = row < N ? row : (N - 1);
      const float* xr = X + (size_t)crow * 128;
#pragma unroll
      for (int ks = 0; ks < 4; ++ks) {
        float4 f0 = *(const float4*)(xr + ks * 32 + q * 8);
        float4 f1 = *(const float4*)(xr + ks * 32 + q * 8 + 4);
        float v[8] = {f0.x, f0.y, f0.z, f0.w, f1.x, f1.y, f1.z, f1.w};
        frag_from8(v, ahi[mt][ks], alo[mt][ks]);
      }
    }

    float4v acc[2][8];
#pragma unroll
    for (int mt = 0; mt < 2; ++mt)
#pragma unroll
      for (int nt = 0; nt < 8; ++nt) acc[mt][nt] = (float4v){0.f, 0.f, 0.f, 0.f};

#pragma unroll
    for (int ks = 0; ks < 4; ++ks) {
      short8v bh[8];
#pragma unroll
      for (int nt = 0; nt < 8; ++nt) {
        int c = nt * 16 + s;
        int off = c * 256 + ((ks * 64 + q * 16) ^ bswz);
        bh[nt] = *(const short8v*)((char*)Whi + off);
      }
#pragma unroll
      for (int nt = 0; nt < 8; ++nt) {
#pragma unroll
        for (int mt = 0; mt < 2; ++mt) {
          acc[mt][nt] = __builtin_amdgcn_mfma_f32_16x16x32_bf16(ahi[mt][ks], bh[nt], acc[mt][nt], 0, 0, 0);
          acc[mt][nt] = __builtin_amdgcn_mfma_f32_16x16x32_bf16(alo[mt][ks], bh[nt], acc[mt][nt], 0, 0, 0);
        }
      }
#pragma unroll
      for (int nt = 0; nt < 8; ++nt) {
        int c = nt * 16 + s;
        int off = c * 256 + ((ks * 64 + q * 16) ^ bswz);
        short8v bl = *(const short8v*)((char*)Wlo + off);
#pragma unroll
        for (int mt = 0; mt < 2; ++mt)
          acc[mt][nt] = __builtin_amdgcn_mfma_f32_16x16x32_bf16(ahi[mt][ks], bl, acc[mt][nt], 0, 0, 0);
      }
    }

#pragma unroll
    for (int mt = 0; mt < 2; ++mt) {
      float4v gacc = (float4v){0.f, 0.f, 0.f, 0.f};
#pragma unroll
      for (int ks = 0; ks < 4; ++ks) {
#pragma unroll
        for (int j = 0; j < 2; ++j) {
          int nt = 2 * ks + j;
          int cl = j * 16 + s;
#pragma unroll
          for (int e = 0; e < 4; ++e)
            hbuf[cl * 17 + q * 4 + e] = fmaxf(acc[mt][nt][e] + bv[nt], 0.f);
        }
        float hv[8];
#pragma unroll
        for (int e = 0; e < 8; ++e) hv[e] = hbuf[(q * 8 + e) * 17 + s];
        short8v hh, hl;
        frag_from8(hv, hh, hl);
        gacc = __builtin_amdgcn_mfma_f32_16x16x32_bf16(hh, woh[ks], gacc, 0, 0, 0);
        gacc = __builtin_amdgcn_mfma_f32_16x16x32_bf16(hl, woh[ks], gacc, 0, 0, 0);
        gacc = __builtin_amdgcn_mfma_f32_16x16x32_bf16(hh, wol[ks], gacc, 0, 0, 0);
      }
      int grow = rowbase + mt * 16 + 4 * q;
#pragma unroll
      for (int e = 0; e < 4; ++e)
        if (grow + e < N) G[(size_t)(grow + e) * 16 + s] = gacc[e];
    }
  }
}

// edge space order: [rby (Erby), dby (Edby), rates (Er), dir (Edir)]
// stage A buckets: user=yd, NU+bd  (bins 0..nbinsA) ; stage B: 2*rd, 2*dd+1 (bins 256+)
__device__ __forceinline__ void edge_decode(
    int i, const int* ys, const int* yd, int Erby,
    const int* bs, const int* bd, int Edby,
    const int* rs, const int* rd, int Er,
    const int* ds, const int* dd,
    int NU, int& src, int& bucket, int& bin)
{
  if (i < Erby)            { src = ys[i]; bucket = yd[i];                 bin = bucket >> BIN_SHIFT; }
  else if (i < Erby + Edby){ int j = i - Erby; src = bs[j]; bucket = NU + bd[j]; bin = bucket >> BIN_SHIFT; }
  else if (i < Erby + Edby + Er) { int j = i - Erby - Edby; src = rs[j]; bucket = 2 * rd[j]; bin = 256 + (bucket >> BIN_SHIFT); }
  else                     { int j = i - Erby - Edby - Er; src = ds[j]; bucket = 2 * dd[j] + 1; bin = 256 + (bucket >> BIN_SHIFT); }
}

// ---------------- fixed-capacity binned fill (no global hist/scan needed) ------------
// cursor[512] starts 0; window for bin = bin*CAPB; per-(block,bin) reservation atomics.
__global__ __launch_bounds__(256) void fill2_kernel(
    const int* __restrict__ ys, const int* __restrict__ yd, int Erby,
    const int* __restrict__ bs, const int* __restrict__ bd, int Edby,
    const int* __restrict__ rs, const int* __restrict__ rd, int Er,
    const int* __restrict__ ds, const int* __restrict__ dd, int Edir,
    int NU, int* __restrict__ cursor,
    unsigned* __restrict__ binnedA, unsigned* __restrict__ binnedB)
{
  __shared__ int h[512];
  __shared__ int base[512];
  const int E = Erby + Edby + Er + Edir;
  const int c0 = blockIdx.x * 4096;
  const int c1 = (c0 + 4096 < E) ? c0 + 4096 : E;
  h[threadIdx.x] = 0; h[threadIdx.x + 256] = 0;
  __syncthreads();
  for (int i = c0 + threadIdx.x; i < c1; i += 256) {
    int src, bucket, bin;
    edge_decode(i, ys, yd, Erby, bs, bd, Edby, rs, rd, Er, ds, dd, NU, src, bucket, bin);
    atomicAdd(&h[bin], 1);
  }
  __syncthreads();
#pragma unroll
  for (int k = threadIdx.x; k < 512; k += 256) {
    int c = h[k];
    base[k] = c ? atomicAdd(&cursor[k], c) : 0;
    h[k] = 0;
  }
  __syncthreads();
  for (int i = c0 + threadIdx.x; i < c1; i += 256) {
    int src, bucket, bin;
    edge_decode(i, ys, yd, Erby, bs, bd, Edby, rs, rd, Er, ds, dd, NU, src, bucket, bin);
    int r = atomicAdd(&h[bin], 1);
    int pos = base[bin] + r;
    if (pos < CAPB) {
      unsigned code = ((unsigned)src << BIN_SHIFT) | (unsigned)(bucket & (SBIN - 1));
      if (bin < 256) binnedA[(size_t)bin * CAPB + pos] = code;
      else           binnedB[(size_t)(bin - 256) * CAPB + pos] = code;
    }
  }
}

// ---------------- scatter + fused stage-A pay --------------------------------------
// One block per bin. LDS hist+scan -> exact per-bucket slots inside the bin's padded
// window; rerank writes ssrc (L2-local). Stage-A blocks then directly compute
// pay = ALPHA*g_self + 0.5*mean(g_m) for their 1024 buckets (ssrc is L2-hot).
__global__ __launch_bounds__(256) void scatter_pay_kernel(
    const unsigned* __restrict__ binnedA, const unsigned* __restrict__ binnedB,
    const int* __restrict__ cursor, int nbinsA, int HA, int HB,
    int* __restrict__ bOffsB, int* __restrict__ bCntB,
    int* __restrict__ ssrcA, int* __restrict__ ssrcB,
    const float* __restrict__ g_m, const float* __restrict__ g_u,
    const float* __restrict__ g_d,
    float* __restrict__ pay_u, float* __restrict__ pay_d, int NU, int ND)
{
  __shared__ int cnt[SBIN];
  __shared__ int pref[SBIN];
  __shared__ int wsum[256];
  const int t = threadIdx.x;
  const bool isA = (int)blockIdx.x < nbinsA;
  const int b = isA ? (int)blockIdx.x : (int)blockIdx.x - nbinsA;
  const unsigned* win = (isA ? binnedA : binnedB) + (size_t)b * CAPB;
  int* ssrc = isA ? ssrcA : ssrcB;
  const size_t wbase = (size_t)b * CAPB;
  int n = cursor[isA ? b : 256 + b];
  if (n > CAPB) n = CAPB;

#pragma unroll
  for (int k = t; k < SBIN; k += 256) cnt[k] = 0;
  __syncthreads();
  for (int i = t; i < n; i += 256)
    atomicAdd(&cnt[win[i] & (SBIN - 1)], 1);
  __syncthreads();
  int c0 = cnt[4 * t], c1 = cnt[4 * t + 1], c2 = cnt[4 * t + 2], c3 = cnt[4 * t + 3];
  int s = c0 + c1 + c2 + c3;
  wsum[t] = s;
  __syncthreads();
  for (int d = 1; d < 256; d <<= 1) {
    int add = (t >= d) ? wsum[t - d] : 0;
    __syncthreads();
    wsum[t] += add;
    __syncthreads();
  }
  int base = wsum[t] - s;
  pref[4 * t]     = base;
  pref[4 * t + 1] = base + c0;
  pref[4 * t + 2] = base + c0 + c1;
  pref[4 * t + 3] = base + c0 + c1 + c2;
  __syncthreads();
  const int gb = b << BIN_SHIFT;
  if (!isA) {
#pragma unroll
    for (int k = t; k < SBIN; k += 256) {
      int bucket = gb + k;
      if (bucket < HB) { bOffsB[bucket] = (int)(wbase + pref[k]); bCntB[bucket] = cnt[k]; }
    }
  }
  __syncthreads();
#pragma unroll
  for (int k = t; k < SBIN; k += 256) cnt[k] = pref[k];
  __syncthreads();
  for (int i = t; i < n; i += 256) {
    unsigned code = win[i];
    int local = code & (SBIN - 1);
    int r = atomicAdd(&cnt[local], 1);
    ssrc[wbase + r] = (int)(code >> BIN_SHIFT);
  }

  if (isA) {
    __syncthreads();   // ssrc writes drained (vmcnt) -> visible via L2 to this block
    const int o = t & 15, g = t >> 4;
    for (int k = g; k < SBIN; k += 16) {
      int bucket = gb + k;
      if (bucket >= HA) break;
      int ck = cnt[k] - pref[k];          // rerank left cnt[k] = pref[k]+count
      size_t start = wbase + pref[k];
      float sum = 0.f;
      for (int j = 0; j < ck; ++j) {
        int src = ssrcA[start + j];
        sum += g_m[(size_t)src * 16 + o];
      }
      float mean = 0.5f * sum / fmaxf((float)ck, 1.f);
      if (bucket < NU)
        pay_u[(size_t)bucket * 16 + o] = ALPHA * g_u[(size_t)bucket * 16 + o] + mean;
      else
        pay_d[(size_t)(bucket - NU) * 16 + o] = ALPHA * g_d[(size_t)(bucket - NU) * 16 + o] + mean;
    }
  }
}

// ---------------- out[m] = b_out + a^2*g_m[m] + mean_rates(pay_u) + mean_dir(pay_d) ---
__global__ __launch_bounds__(256) void final_kernel(
    const float* __restrict__ gm, const float* __restrict__ pay_u,
    const float* __restrict__ pay_d,
    const int* __restrict__ bOffs, const int* __restrict__ bCnt,
    const int* __restrict__ ssrc,
    const float* __restrict__ bo, float* __restrict__ out, int NM)
{
  int tid = blockIdx.x * 256 + threadIdx.x;
  int m = tid >> 4, o = tid & 15;
  if (m >= NM) return;
  int s0 = bOffs[2 * m], c0 = bCnt[2 * m];
  float sr = 0.f;
  for (int j = 0; j < c0; ++j) sr += pay_u[(size_t)ssrc[s0 + j] * 16 + o];
  int s1 = bOffs[2 * m + 1], c1 = bCnt[2 * m + 1];
  float sd = 0.f;
  for (int j = 0; j < c1; ++j) sd += pay_d[(size_t)ssrc[s1 + j] * 16 + o];
  out[(size_t)m * 16 + o] = bo[o] + ALPHA * ALPHA * gm[(size_t)m * 16 + o]
                          + sr / fmaxf((float)c0, 1.f) + sd / fmaxf((float)c1, 1.f);
}

extern "C" void kernel_launch(void* const* d_in, const int* in_sizes, int n_in,
                              void* d_out, int out_size, void* d_ws, size_t ws_size,
                              hipStream_t stream)
{
  const float* x_user  = (const float*)d_in[0];
  const float* x_movie = (const float*)d_in[1];
  const float* x_dir   = (const float*)d_in[2];
  const int* rates_src = (const int*)d_in[3];
  const int* rates_dst = (const int*)d_in[4];
  const int* rby_src   = (const int*)d_in[5];
  const int* rby_dst   = (const int*)d_in[6];
  const int* dir_src   = (const int*)d_in[7];
  const int* dir_dst   = (const int*)d_in[8];
  const int* dby_src   = (const int*)d_in[9];
  const int* dby_dst   = (const int*)d_in[10];
  const float* W_user  = (const float*)d_in[11];
  const float* b_user  = (const float*)d_in[12];
  const float* W_movie = (const float*)d_in[13];
  const float* b_movie = (const float*)d_in[14];
  const float* W_dir   = (const float*)d_in[15];
  const float* b_dir   = (const float*)d_in[16];
  const float* W_out   = (const float*)d_in[17];
  const float* b_out   = (const float*)d_in[18];

  const int NU = in_sizes[0] / 128, NM = in_sizes[1] / 128, ND = in_sizes[2] / 128;
  const int Er = in_sizes[3], Erby = in_sizes[5], Edir = in_sizes[7], Edby = in_sizes[9];

  const int E  = Er + Edir + Erby + Edby;
  const int HA = NU + ND;
  const int HB = 2 * NM;
  const int nbinsA = (HA + SBIN - 1) >> BIN_SHIFT;   // <= 256
  const int nbinsB = (HB + SBIN - 1) >> BIN_SHIFT;   // <= 256

  // ---- workspace layout
  char* w = (char*)d_ws;
  size_t off = 0;
  auto take = [&](size_t bytes) { char* p = w + off; off += (bytes + 255) & ~(size_t)255; return p; };
  float* g_u   = (float*)take((size_t)NU * 16 * 4);
  float* g_m   = (float*)take((size_t)NM * 16 * 4);
  float* g_d   = (float*)take((size_t)ND * 16 * 4);
  float* pay_u = (float*)take((size_t)NU * 16 * 4);
  float* pay_d = (float*)take((size_t)ND * 16 * 4);
  int* cursor     = (int*)take(512 * 4);             // zeroed (per-bin counts)
  int* bOffsB     = (int*)take((size_t)HB * 4);
  int* bCntB      = (int*)take((size_t)HB * 4);
  unsigned* binnedA = (unsigned*)take((size_t)nbinsA * CAPB * 4);
  unsigned* binnedB = (unsigned*)take((size_t)nbinsB * CAPB * 4);
  int* ssrcA      = (int*)take((size_t)nbinsA * CAPB * 4);
  int* ssrcB      = (int*)take((size_t)nbinsB * CAPB * 4);
  if (off > ws_size) return;

  // 1. zero per-bin counters
  hipMemsetAsync(cursor, 0, 512 * 4, stream);

  // 2. fixed-capacity binned fill (clustered code writes; no hist/scan needed)
  fill2_kernel<<<(E + 4095) / 4096, 256, 0, stream>>>(
      rby_src, rby_dst, Erby, dby_src, dby_dst, Edby,
      rates_src, rates_dst, Er, dir_src, dir_dst, Edir, NU,
      cursor, binnedA, binnedB);

  // 3. one MFMA launch for all three ntypes (proportional static partition of 512 blks)
  {
    long long cu = (NU + 127) >> 7, cm = (NM + 127) >> 7, cd = (ND + 127) >> 7;
    long long ct = cu + cm + cd;
    int bu = (int)((512 * cu + ct / 2) / ct);
    int bm = (int)((512 * cm + ct / 2) / ct);
    if (bu < 1) bu = 1;
    if (bm < 1) bm = 1;
    if (bu + bm > 510) { bu = 510 * bu / (bu + bm); bm = 510 - bu; }
    fused_mfma3_kernel<<<512, 256, 0, stream>>>(
        x_user, x_movie, x_dir, W_user, W_movie, W_dir,
        b_user, b_movie, b_dir, W_out, g_u, g_m, g_d,
        NU, NM, ND, bu, bm);
  }

  // 4. scatter -> exact per-bucket CSR inside padded windows; stage-A blocks also
  //    compute pay_u/pay_d directly (ssrc + pref are L2/LDS-hot)
  scatter_pay_kernel<<<nbinsA + nbinsB, 256, 0, stream>>>(
      binnedA, binnedB, cursor, nbinsA, HA, HB,
      bOffsB, bCntB, ssrcA, ssrcB,
      g_m, g_u, g_d, pay_u, pay_d, NU, ND);

  // 5. out = b_out + a^2*g_m + mean_rates(pay_u) + mean_dir(pay_d)
  final_kernel<<<(NM * 16 + 255) / 256, 256, 0, stream>>>(
      g_m, pay_u, pay_d, bOffsB, bCntB, ssrcB, b_out, (float*)d_out, NM);
}

// Round 12
// 280.749 us; speedup vs baseline: 1.3180x; 1.3180x over previous
//
#include <hip/hip_runtime.h>

#define ALPHA 0.01f
#define BIN_SHIFT 10
#define SBIN 1024            // buckets per bin; <=256 bins per stage

typedef __attribute__((ext_vector_type(8))) short short8v;   // 8 x bf16 bits (4 VGPR)
typedef __attribute__((ext_vector_type(4))) float float4v;   // MFMA acc

// split fp32 -> bf16 hi + bf16 lo (truncation; residual capture => ~2^-24 total rel err)
__device__ __forceinline__ void bsplit(float x, unsigned short& hi, unsigned short& lo) {
  unsigned u = __float_as_uint(x);
  hi = (unsigned short)(u >> 16);
  float r = x - __uint_as_float(u & 0xFFFF0000u);
  lo = (unsigned short)(__float_as_uint(r) >> 16);
}

__device__ __forceinline__ void frag_from8(const float* v, short8v& hi, short8v& lo) {
#pragma unroll
  for (int e = 0; e < 8; ++e) {
    unsigned short h, l;
    bsplit(v[e], h, l);
    hi[e] = (short)h;
    lo[e] = (short)l;
  }
}

// ---------------- fused MFMA for ALL ntypes: G = relu(X @ W^T + b) @ Wo^T -------------
// SWAP-TRANSPOSE version: main GEMM computes h^T = W·x^T (operands swapped; A/B frag
// layouts are index-identical). Lane then holds h[m=s][c=16nt+4q+reg] -- a valid
// B-fragment for the projection MFMA given Wo staged with matching k-permutation
// c(q,e)=32j+(e<4?4q+e:16+4q+e-4). No LDS h-transpose at all.
__global__ __launch_bounds__(256, 2) void fused_mfma3_kernel(
    const float* __restrict__ Xu, const float* __restrict__ Xm, const float* __restrict__ Xd,
    const float* __restrict__ Wu, const float* __restrict__ Wm, const float* __restrict__ Wd,
    const float* __restrict__ Bu, const float* __restrict__ Bm, const float* __restrict__ Bd,
    const float* __restrict__ Wo,
    float* __restrict__ Gu, float* __restrict__ Gm, float* __restrict__ Gd,
    int NU, int NM, int ND, int bu, int bm)
{
  __shared__ char smem[65536 + 8192] __attribute__((aligned(16)));
  unsigned short* Whi = (unsigned short*)smem;
  unsigned short* Wlo = (unsigned short*)(smem + 32768);
  unsigned short* WoHi = (unsigned short*)(smem + 65536);
  unsigned short* WoLo = (unsigned short*)(smem + 65536 + 4096);

  const float *X, *W, *B;
  float* G;
  int N, bid, nbk;
  if ((int)blockIdx.x < bu)            { X = Xu; W = Wu; B = Bu; G = Gu; N = NU; bid = blockIdx.x;            nbk = bu; }
  else if ((int)blockIdx.x < bu + bm)  { X = Xm; W = Wm; B = Bm; G = Gm; N = NM; bid = blockIdx.x - bu;       nbk = bm; }
  else                                 { X = Xd; W = Wd; B = Bd; G = Gd; N = ND; bid = blockIdx.x - bu - bm;  nbk = gridDim.x - bu - bm; }

  const int t = threadIdx.x;
  const int lane = t & 63;
  const int s = lane & 15;
  const int q = lane >> 4;

  // ---- stage W (hi/lo, swizzled) : 8192 col-pairs over 256 threads
#pragma unroll
  for (int i = 0; i < 32; ++i) {
    int p = i * 256 + t;
    int row = p >> 6, c2 = p & 63;
    float w0 = W[row * 128 + c2 * 2];
    float w1 = W[row * 128 + c2 * 2 + 1];
    unsigned short h0, l0, h1, l1;
    bsplit(w0, h0, l0); bsplit(w1, h1, l1);
    int u32idx = row * 64 + ((((c2 * 4) ^ ((row & 7) << 4))) >> 2);
    ((unsigned*)Whi)[u32idx] = (unsigned)h0 | ((unsigned)h1 << 16);
    ((unsigned*)Wlo)[u32idx] = (unsigned)l0 | ((unsigned)l1 << 16);
  }
  // ---- stage Wo PERMUTED: WoP[o][k'=8q+e] = Wo[o][c(q,e)], c = 32j + (e<4?4q+e:16+4q+e-4)
#pragma unroll
  for (int i = 0; i < 4; ++i) {
    int p = i * 256 + t;
    int row = p >> 6, c2 = p & 63;        // dest u32 pair: k' = 2*c2, 2*c2+1
    int kp = 2 * c2;
    int j = kp >> 5;
    int t5 = kp & 31;
    int qq = t5 >> 3, e = t5 & 7;         // e even
    int c0 = 32 * j + (e < 4 ? 4 * qq + e : 16 + 4 * qq + (e - 4));
    float w0 = Wo[row * 128 + c0];
    float w1 = Wo[row * 128 + c0 + 1];
    unsigned short h0, l0, h1, l1;
    bsplit(w0, h0, l0); bsplit(w1, h1, l1);
    int u32idx = row * 64 + ((((c2 * 4) ^ ((row & 7) << 4))) >> 2);
    ((unsigned*)WoHi)[u32idx] = (unsigned)h0 | ((unsigned)h1 << 16);
    ((unsigned*)WoLo)[u32idx] = (unsigned)l0 | ((unsigned)l1 << 16);
  }
  __syncthreads();

  // ---- hoist WoP fragments (A-operand: lane holds WoP[o=s][k'=ks*32+q*8 .. +8])
  short8v woh[4], wol[4];
  const int woswz = (s & 7) << 4;
#pragma unroll
  for (int ks = 0; ks < 4; ++ks) {
    int off = s * 256 + ((ks * 64 + q * 16) ^ woswz);
    woh[ks] = *(const short8v*)((char*)WoHi + off);
    wol[ks] = *(const short8v*)((char*)WoLo + off);
  }
  // ---- bias per lane: bq[nt] = B[nt*16 + 4q .. +4]  (channel c = 16nt+4q+e)
  float4 bq[8];
#pragma unroll
  for (int nt = 0; nt < 8; ++nt) bq[nt] = *(const float4*)(B + nt * 16 + 4 * q);

  const int nchunks = (N + 127) >> 7;
  const int bswz = (s & 7) << 4;
  const int wave = t >> 6;

  for (int chunk = bid; chunk < nchunks; chunk += nbk) {
    const int rowbase = chunk * 128 + wave * 32;

    // ---- x fragments (B-operand after swap; same per-lane data as before)
    short8v ahi[2][4], alo[2][4];
#pragma unroll
    for (int mt = 0; mt < 2; ++mt) {
      int row = rowbase + mt * 16 + s;
      int crow = row < N ? row : (N - 1);
      const float* xr = X + (size_t)crow * 128;
#pragma unroll
      for (int ks = 0; ks < 4; ++ks) {
        float4 f0 = *(const float4*)(xr + ks * 32 + q * 8);
        float4 f1 = *(const float4*)(xr + ks * 32 + q * 8 + 4);
        float v[8] = {f0.x, f0.y, f0.z, f0.w, f1.x, f1.y, f1.z, f1.w};
        frag_from8(v, ahi[mt][ks], alo[mt][ks]);
      }
    }

    // ---- main GEMM (swapped): acc[mt][nt] = h^T tile, rows c=16nt+4q+reg, cols m=16mt+s
    float4v acc[2][8];
#pragma unroll
    for (int mt = 0; mt < 2; ++mt)
#pragma unroll
      for (int nt = 0; nt < 8; ++nt) acc[mt][nt] = (float4v){0.f, 0.f, 0.f, 0.f};

#pragma unroll
    for (int ks = 0; ks < 4; ++ks) {
      short8v bh[8];
#pragma unroll
      for (int nt = 0; nt < 8; ++nt) {
        int c = nt * 16 + s;
        int off = c * 256 + ((ks * 64 + q * 16) ^ bswz);
        bh[nt] = *(const short8v*)((char*)Whi + off);
      }
#pragma unroll
      for (int nt = 0; nt < 8; ++nt) {
#pragma unroll
        for (int mt = 0; mt < 2; ++mt) {
          acc[mt][nt] = __builtin_amdgcn_mfma_f32_16x16x32_bf16(bh[nt], ahi[mt][ks], acc[mt][nt], 0, 0, 0);
          acc[mt][nt] = __builtin_amdgcn_mfma_f32_16x16x32_bf16(bh[nt], alo[mt][ks], acc[mt][nt], 0, 0, 0);
        }
      }
#pragma unroll
      for (int nt = 0; nt < 8; ++nt) {
        int c = nt * 16 + s;
        int off = c * 256 + ((ks * 64 + q * 16) ^ bswz);
        short8v bl = *(const short8v*)((char*)Wlo + off);
#pragma unroll
        for (int mt = 0; mt < 2; ++mt)
          acc[mt][nt] = __builtin_amdgcn_mfma_f32_16x16x32_bf16(bl, ahi[mt][ks], acc[mt][nt], 0, 0, 0);
      }
    }

    // ---- projection entirely in-register: g^T = WoP · h^T (k-permutation matched)
#pragma unroll
    for (int mt = 0; mt < 2; ++mt) {
      float4v gacc = (float4v){0.f, 0.f, 0.f, 0.f};
#pragma unroll
      for (int j = 0; j < 4; ++j) {
        float hv[8];
#pragma unroll
        for (int e = 0; e < 4; ++e) {
          float b0 = (e == 0) ? bq[2 * j].x : (e == 1) ? bq[2 * j].y : (e == 2) ? bq[2 * j].z : bq[2 * j].w;
          float b1 = (e == 0) ? bq[2 * j + 1].x : (e == 1) ? bq[2 * j + 1].y : (e == 2) ? bq[2 * j + 1].z : bq[2 * j + 1].w;
          hv[e]     = fmaxf(acc[mt][2 * j][e] + b0, 0.f);
          hv[e + 4] = fmaxf(acc[mt][2 * j + 1][e] + b1, 0.f);
        }
        short8v hh, hl;
        frag_from8(hv, hh, hl);
        gacc = __builtin_amdgcn_mfma_f32_16x16x32_bf16(woh[j], hh, gacc, 0, 0, 0);
        gacc = __builtin_amdgcn_mfma_f32_16x16x32_bf16(woh[j], hl, gacc, 0, 0, 0);
        gacc = __builtin_amdgcn_mfma_f32_16x16x32_bf16(wol[j], hh, gacc, 0, 0, 0);
      }
      // lane holds g[m = rowbase+mt*16+s][o = 4q..4q+3] -> one float4 store
      int grow = rowbase + mt * 16 + s;
      if (grow < N)
        *(float4*)(G + (size_t)grow * 16 + 4 * q) =
            make_float4(gacc[0], gacc[1], gacc[2], gacc[3]);
    }
  }
}

// edge space order: [rby (Erby), dby (Edby), rates (Er), dir (Edir)]
__device__ __forceinline__ void edge_decode(
    int i, const int* ys, const int* yd, int Erby,
    const int* bs, const int* bd, int Edby,
    const int* rs, const int* rd, int Er,
    const int* ds, const int* dd,
    int NU, int& src, int& bucket, int& bin)
{
  if (i < Erby)            { src = ys[i]; bucket = yd[i];                 bin = bucket >> BIN_SHIFT; }
  else if (i < Erby + Edby){ int j = i - Erby; src = bs[j]; bucket = NU + bd[j]; bin = bucket >> BIN_SHIFT; }
  else if (i < Erby + Edby + Er) { int j = i - Erby - Edby; src = rs[j]; bucket = 2 * rd[j]; bin = 256 + (bucket >> BIN_SHIFT); }
  else                     { int j = i - Erby - Edby - Er; src = ds[j]; bucket = 2 * dd[j] + 1; bin = 256 + (bucket >> BIN_SHIFT); }
}

// ---------------- combined coarse histogram (both stages, 512 LDS bins) --------------
__global__ __launch_bounds__(256) void hist2_kernel(
    const int* __restrict__ ys, const int* __restrict__ yd, int Erby,
    const int* __restrict__ bs, const int* __restrict__ bd, int Edby,
    const int* __restrict__ rs, const int* __restrict__ rd, int Er,
    const int* __restrict__ ds, const int* __restrict__ dd, int Edir,
    int NU, int* __restrict__ binHist)
{
  __shared__ int h[512];
  h[threadIdx.x] = 0; h[threadIdx.x + 256] = 0;
  __syncthreads();
  const int E = Erby + Edby + Er + Edir;
  for (int i = blockIdx.x * 256 + threadIdx.x; i < E; i += gridDim.x * 256) {
    int src, bucket, bin;
    edge_decode(i, ys, yd, Erby, bs, bd, Edby, rs, rd, Er, ds, dd, NU, src, bucket, bin);
    atomicAdd(&h[bin], 1);
  }
  __syncthreads();
  int v0 = h[threadIdx.x], v1 = h[threadIdx.x + 256];
  if (v0) atomicAdd(&binHist[threadIdx.x], v0);
  if (v1) atomicAdd(&binHist[threadIdx.x + 256], v1);
}

// ---------------- scans for both stages in one block ---------------------------------
__global__ __launch_bounds__(256) void scan2s_kernel(
    const int* __restrict__ binHist, int* __restrict__ binStartA,
    int* __restrict__ binStartB, int* __restrict__ cursor)
{
  __shared__ int tmp[256];
  const int t = threadIdx.x;
#pragma unroll
  for (int stage = 0; stage < 2; ++stage) {
    int v = binHist[stage * 256 + t];
    tmp[t] = v;
    __syncthreads();
    for (int d = 1; d < 256; d <<= 1) {
      int add = (t >= d) ? tmp[t - d] : 0;
      __syncthreads();
      tmp[t] += add;
      __syncthreads();
    }
    int excl = tmp[t] - v;
    int* bs = stage ? binStartB : binStartA;
    bs[t] = excl;
    cursor[stage * 256 + t] = excl;
    if (t == 255) bs[256] = tmp[255];
    __syncthreads();
  }
}

// ---------------- combined binned fill (both stages) ---------------------------------
__global__ __launch_bounds__(256) void fill2_kernel(
    const int* __restrict__ ys, const int* __restrict__ yd, int Erby,
    const int* __restrict__ bs, const int* __restrict__ bd, int Edby,
    const int* __restrict__ rs, const int* __restrict__ rd, int Er,
    const int* __restrict__ ds, const int* __restrict__ dd, int Edir,
    int NU, int* __restrict__ cursor,
    unsigned* __restrict__ binnedA, unsigned* __restrict__ binnedB)
{
  __shared__ int h[512];
  __shared__ int base[512];
  const int E = Erby + Edby + Er + Edir;
  const int c0 = blockIdx.x * 4096;
  const int c1 = (c0 + 4096 < E) ? c0 + 4096 : E;
  h[threadIdx.x] = 0; h[threadIdx.x + 256] = 0;
  __syncthreads();
  for (int i = c0 + threadIdx.x; i < c1; i += 256) {
    int src, bucket, bin;
    edge_decode(i, ys, yd, Erby, bs, bd, Edby, rs, rd, Er, ds, dd, NU, src, bucket, bin);
    atomicAdd(&h[bin], 1);
  }
  __syncthreads();
#pragma unroll
  for (int k = threadIdx.x; k < 512; k += 256) {
    int c = h[k];
    base[k] = c ? atomicAdd(&cursor[k], c) : 0;
    h[k] = 0;
  }
  __syncthreads();
  for (int i = c0 + threadIdx.x; i < c1; i += 256) {
    int src, bucket, bin;
    edge_decode(i, ys, yd, Erby, bs, bd, Edby, rs, rd, Er, ds, dd, NU, src, bucket, bin);
    int r = atomicAdd(&h[bin], 1);
    unsigned code = ((unsigned)src << BIN_SHIFT) | (unsigned)(bucket & (SBIN - 1));
    if (bin < 256) binnedA[base[bin] + r] = code;
    else           binnedB[base[bin] + r] = code;
  }
}

// ---------------- combined bin scatter (grid = nbinsA + nbinsB) ----------------------
__global__ __launch_bounds__(256) void scatter2_kernel(
    const unsigned* __restrict__ binnedA, const int* __restrict__ binStartA, int nbinsA, int HA,
    const unsigned* __restrict__ binnedB, const int* __restrict__ binStartB, int HB,
    int* __restrict__ bOffsA, int* __restrict__ bCntA,
    int* __restrict__ bOffsB, int* __restrict__ bCntB,
    int* __restrict__ ssrcA, int* __restrict__ ssrcB)
{
  __shared__ int cnt[SBIN];
  __shared__ int pref[SBIN];
  __shared__ int wsum[256];
  const int t = threadIdx.x;
  const unsigned* binned; const int* binStart;
  int* bOffs; int* bCnt; int* ssrc;
  int b, nbuckets;
  if ((int)blockIdx.x < nbinsA) {
    b = blockIdx.x; binned = binnedA; binStart = binStartA;
    bOffs = bOffsA; bCnt = bCntA; ssrc = ssrcA; nbuckets = HA;
  } else {
    b = blockIdx.x - nbinsA; binned = binnedB; binStart = binStartB;
    bOffs = bOffsB; bCnt = bCntB; ssrc = ssrcB; nbuckets = HB;
  }
  const int s0 = binStart[b], s1 = binStart[b + 1];
#pragma unroll
  for (int k = t; k < SBIN; k += 256) cnt[k] = 0;
  __syncthreads();
  for (int i = s0 + t; i < s1; i += 256)
    atomicAdd(&cnt[binned[i] & (SBIN - 1)], 1);
  __syncthreads();
  int c0 = cnt[4 * t], c1 = cnt[4 * t + 1], c2 = cnt[4 * t + 2], c3 = cnt[4 * t + 3];
  int s = c0 + c1 + c2 + c3;
  wsum[t] = s;
  __syncthreads();
  for (int d = 1; d < 256; d <<= 1) {
    int add = (t >= d) ? wsum[t - d] : 0;
    __syncthreads();
    wsum[t] += add;
    __syncthreads();
  }
  int base = wsum[t] - s;
  pref[4 * t]     = base;
  pref[4 * t + 1] = base + c0;
  pref[4 * t + 2] = base + c0 + c1;
  pref[4 * t + 3] = base + c0 + c1 + c2;
  __syncthreads();
  const int gb = b << BIN_SHIFT;
#pragma unroll
  for (int k = t; k < SBIN; k += 256) {
    int bucket = gb + k;
    if (bucket < nbuckets) { bOffs[bucket] = s0 + pref[k]; bCnt[bucket] = cnt[k]; }
  }
  __syncthreads();
#pragma unroll
  for (int k = t; k < SBIN; k += 256) cnt[k] = pref[k];
  __syncthreads();
  for (int i = s0 + t; i < s1; i += 256) {
    unsigned code = binned[i];
    int local = code & (SBIN - 1);
    int r = atomicAdd(&cnt[local], 1);
    ssrc[s0 + r] = (int)(code >> BIN_SHIFT);
  }
}

// ---------------- fused pay gather for users + directors -----------------------------
__global__ __launch_bounds__(256) void gather_pay2_kernel(
    const float* __restrict__ g_m, const float* __restrict__ g_u,
    const float* __restrict__ g_d,
    const int* __restrict__ bOffsA, const int* __restrict__ bCntA,
    const int* __restrict__ ssrcA,
    float* __restrict__ pay_u, float* __restrict__ pay_d, int NU, int ND)
{
  int tid = blockIdx.x * 256 + threadIdx.x;
  int node = tid >> 4, o = tid & 15;
  if (node >= NU + ND) return;
  int start = bOffsA[node], cnt = bCntA[node];
  float sum = 0.f;
  for (int j = 0; j < cnt; ++j) {
    int s = ssrcA[start + j];
    sum += g_m[(size_t)s * 16 + o];
  }
  float mean = 0.5f * sum / fmaxf((float)cnt, 1.f);
  if (node < NU)
    pay_u[(size_t)node * 16 + o] = ALPHA * g_u[(size_t)node * 16 + o] + mean;
  else {
    int nn = node - NU;
    pay_d[(size_t)nn * 16 + o] = ALPHA * g_d[(size_t)nn * 16 + o] + mean;
  }
}

// ---------------- out[m] = b_out + a^2*g_m[m] + mean_rates(pay_u) + mean_dir(pay_d) ---
__global__ __launch_bounds__(256) void final_kernel(
    const float* __restrict__ gm, const float* __restrict__ pay_u,
    const float* __restrict__ pay_d,
    const int* __restrict__ bOffs, const int* __restrict__ bCnt,
    const int* __restrict__ ssrc,
    const float* __restrict__ bo, float* __restrict__ out, int NM)
{
  int tid = blockIdx.x * 256 + threadIdx.x;
  int m = tid >> 4, o = tid & 15;
  if (m >= NM) return;
  int s0 = bOffs[2 * m], c0 = bCnt[2 * m];
  float sr = 0.f;
  for (int j = 0; j < c0; ++j) sr += pay_u[(size_t)ssrc[s0 + j] * 16 + o];
  int s1 = bOffs[2 * m + 1], c1 = bCnt[2 * m + 1];
  float sd = 0.f;
  for (int j = 0; j < c1; ++j) sd += pay_d[(size_t)ssrc[s1 + j] * 16 + o];
  out[(size_t)m * 16 + o] = bo[o] + ALPHA * ALPHA * gm[(size_t)m * 16 + o]
                          + sr / fmaxf((float)c0, 1.f) + sd / fmaxf((float)c1, 1.f);
}

extern "C" void kernel_launch(void* const* d_in, const int* in_sizes, int n_in,
                              void* d_out, int out_size, void* d_ws, size_t ws_size,
                              hipStream_t stream)
{
  const float* x_user  = (const float*)d_in[0];
  const float* x_movie = (const float*)d_in[1];
  const float* x_dir   = (const float*)d_in[2];
  const int* rates_src = (const int*)d_in[3];
  const int* rates_dst = (const int*)d_in[4];
  const int* rby_src   = (const int*)d_in[5];
  const int* rby_dst   = (const int*)d_in[6];
  const int* dir_src   = (const int*)d_in[7];
  const int* dir_dst   = (const int*)d_in[8];
  const int* dby_src   = (const int*)d_in[9];
  const int* dby_dst   = (const int*)d_in[10];
  const float* W_user  = (const float*)d_in[11];
  const float* b_user  = (const float*)d_in[12];
  const float* W_movie = (const float*)d_in[13];
  const float* b_movie = (const float*)d_in[14];
  const float* W_dir   = (const float*)d_in[15];
  const float* b_dir   = (const float*)d_in[16];
  const float* W_out   = (const float*)d_in[17];
  const float* b_out   = (const float*)d_in[18];

  const int NU = in_sizes[0] / 128, NM = in_sizes[1] / 128, ND = in_sizes[2] / 128;
  const int Er = in_sizes[3], Erby = in_sizes[5], Edir = in_sizes[7], Edby = in_sizes[9];

  const int EA = Erby + Edby;                 // stage A edges (movies -> users/dirs)
  const int EB = Er + Edir;                   // stage B edges (users/dirs -> movies)
  const int E  = EA + EB;
  const int HA = NU + ND;
  const int HB = 2 * NM;
  const int nbinsA = (HA + SBIN - 1) >> BIN_SHIFT;   // <= 256
  const int nbinsB = (HB + SBIN - 1) >> BIN_SHIFT;   // <= 256

  // ---- workspace layout
  char* w = (char*)d_ws;
  size_t off = 0;
  auto take = [&](size_t bytes) { char* p = w + off; off += (bytes + 255) & ~(size_t)255; return p; };
  float* g_u   = (float*)take((size_t)NU * 16 * 4);
  float* g_m   = (float*)take((size_t)NM * 16 * 4);
  float* g_d   = (float*)take((size_t)ND * 16 * 4);
  float* pay_u = (float*)take((size_t)NU * 16 * 4);
  float* pay_d = (float*)take((size_t)ND * 16 * 4);
  int* binHist    = (int*)take(512 * 4);      // zeroed
  int* binStartA  = (int*)take(257 * 4);
  int* binStartB  = (int*)take(257 * 4);
  int* cursor     = (int*)take(512 * 4);
  int* bOffsA     = (int*)take((size_t)HA * 4);
  int* bCntA      = (int*)take((size_t)HA * 4);
  int* bOffsB     = (int*)take((size_t)HB * 4);
  int* bCntB      = (int*)take((size_t)HB * 4);
  unsigned* binnedA = (unsigned*)take((size_t)EA * 4);
  unsigned* binnedB = (unsigned*)take((size_t)EB * 4);
  int* ssrcA      = (int*)take((size_t)EA * 4);
  int* ssrcB      = (int*)take((size_t)EB * 4);
  if (off > ws_size) return;

  // 1. zero 512-bin histogram
  hipMemsetAsync(binHist, 0, 512 * 4, stream);

  // 2. combined histogram (both stages, one pass over all 4 lists)
  hist2_kernel<<<512, 256, 0, stream>>>(
      rby_src, rby_dst, Erby, dby_src, dby_dst, Edby,
      rates_src, rates_dst, Er, dir_src, dir_dst, Edir, NU, binHist);

  // 3. both scans in one block
  scan2s_kernel<<<1, 256, 0, stream>>>(binHist, binStartA, binStartB, cursor);

  // 4. combined binned fill (clustered code writes)
  fill2_kernel<<<(E + 4095) / 4096, 256, 0, stream>>>(
      rby_src, rby_dst, Erby, dby_src, dby_dst, Edby,
      rates_src, rates_dst, Er, dir_src, dir_dst, Edir, NU,
      cursor, binnedA, binnedB);

  // 5. combined bin scatter -> exact CSR + per-bucket offs/cnt
  scatter2_kernel<<<nbinsA + nbinsB, 256, 0, stream>>>(
      binnedA, binStartA, nbinsA, HA, binnedB, binStartB, HB,
      bOffsA, bCntA, bOffsB, bCntB, ssrcA, ssrcB);

  // 6. one MFMA launch for all three ntypes (proportional static partition of 512 blks)
  {
    long long cu = (NU + 127) >> 7, cm = (NM + 127) >> 7, cd = (ND + 127) >> 7;
    long long ct = cu + cm + cd;
    int bu = (int)((512 * cu + ct / 2) / ct);
    int bm = (int)((512 * cm + ct / 2) / ct);
    if (bu < 1) bu = 1;
    if (bm < 1) bm = 1;
    if (bu + bm > 510) { bu = 510 * bu / (bu + bm); bm = 510 - bu; }
    fused_mfma3_kernel<<<512, 256, 0, stream>>>(
        x_user, x_movie, x_dir, W_user, W_movie, W_dir,
        b_user, b_movie, b_dir, W_out, g_u, g_m, g_d,
        NU, NM, ND, bu, bm);
  }

  // 7. fused pay gather (users + directors)
  gather_pay2_kernel<<<((NU + ND) * 16 + 255) / 256, 256, 0, stream>>>(
      g_m, g_u, g_d, bOffsA, bCntA, ssrcA, pay_u, pay_d, NU, ND);

  // 8. out = b_out + a^2*g_m + mean_rates(pay_u) + mean_dir(pay_d)
  final_kernel<<<(NM * 16 + 255) / 256, 256, 0, stream>>>(
      g_m, pay_u, pay_d, bOffsB, bCntB, ssrcB, b_out, (float*)d_out, NM);
}

// Round 13
// 159.837 us; speedup vs baseline: 2.3150x; 1.7565x over previous
//
#include <hip/hip_runtime.h>

#define ALPHA 0.01f
#define BIN_SHIFT 10
#define SBIN 1024            // buckets per bin; <=256 bins per stage
#define CAPB 8192            // fixed edge capacity per bin window (avg load ~3.4K)

typedef __attribute__((ext_vector_type(8))) short short8v;   // 8 x bf16 bits (4 VGPR)
typedef __attribute__((ext_vector_type(4))) float float4v;   // MFMA acc

// split fp32 -> bf16 hi + bf16 lo (truncation; residual capture => ~2^-24 total rel err)
__device__ __forceinline__ void bsplit(float x, unsigned short& hi, unsigned short& lo) {
  unsigned u = __float_as_uint(x);
  hi = (unsigned short)(u >> 16);
  float r = x - __uint_as_float(u & 0xFFFF0000u);
  lo = (unsigned short)(__float_as_uint(r) >> 16);
}

__device__ __forceinline__ void frag_from8(const float* v, short8v& hi, short8v& lo) {
#pragma unroll
  for (int e = 0; e < 8; ++e) {
    unsigned short h, l;
    bsplit(v[e], h, l);
    hi[e] = (short)h;
    lo[e] = (short)l;
  }
}

// ---------------- fused MFMA for ALL ntypes: G = relu(X @ W^T + b) @ Wo^T -------------
// (round-8 validated form: 73 us, VGPR 112 — do not touch)
__global__ __launch_bounds__(256, 2) void fused_mfma3_kernel(
    const float* __restrict__ Xu, const float* __restrict__ Xm, const float* __restrict__ Xd,
    const float* __restrict__ Wu, const float* __restrict__ Wm, const float* __restrict__ Wd,
    const float* __restrict__ Bu, const float* __restrict__ Bm, const float* __restrict__ Bd,
    const float* __restrict__ Wo,
    float* __restrict__ Gu, float* __restrict__ Gm, float* __restrict__ Gd,
    int NU, int NM, int ND, int bu, int bm)
{
  __shared__ char smem[65536 + 10368] __attribute__((aligned(16)));
  unsigned short* Whi = (unsigned short*)smem;
  unsigned short* Wlo = (unsigned short*)(smem + 32768);
  unsigned short* WoHi = (unsigned short*)(smem + 65536);
  unsigned short* WoLo = (unsigned short*)(smem + 65536 + 4096);

  const float *X, *W, *B;
  float* G;
  int N, bid, nbk;
  if ((int)blockIdx.x < bu)            { X = Xu; W = Wu; B = Bu; G = Gu; N = NU; bid = blockIdx.x;            nbk = bu; }
  else if ((int)blockIdx.x < bu + bm)  { X = Xm; W = Wm; B = Bm; G = Gm; N = NM; bid = blockIdx.x - bu;       nbk = bm; }
  else                                 { X = Xd; W = Wd; B = Bd; G = Gd; N = ND; bid = blockIdx.x - bu - bm;  nbk = gridDim.x - bu - bm; }

  const int t = threadIdx.x;
  const int wave = t >> 6;
  const int lane = t & 63;
  const int s = lane & 15;
  const int q = lane >> 4;
  float* hbuf = (float*)(smem + 65536 + wave * 2176);  // [32][17] f32, per-wave

#pragma unroll
  for (int i = 0; i < 32; ++i) {
    int p = i * 256 + t;
    int row = p >> 6, c2 = p & 63;
    float w0 = W[row * 128 + c2 * 2];
    float w1 = W[row * 128 + c2 * 2 + 1];
    unsigned short h0, l0, h1, l1;
    bsplit(w0, h0, l0); bsplit(w1, h1, l1);
    int u32idx = row * 64 + ((((c2 * 4) ^ ((row & 7) << 4))) >> 2);
    ((unsigned*)Whi)[u32idx] = (unsigned)h0 | ((unsigned)h1 << 16);
    ((unsigned*)Wlo)[u32idx] = (unsigned)l0 | ((unsigned)l1 << 16);
  }
#pragma unroll
  for (int i = 0; i < 4; ++i) {
    int p = i * 256 + t;
    int row = p >> 6, c2 = p & 63;
    float w0 = Wo[row * 128 + c2 * 2];
    float w1 = Wo[row * 128 + c2 * 2 + 1];
    unsigned short h0, l0, h1, l1;
    bsplit(w0, h0, l0); bsplit(w1, h1, l1);
    int u32idx = row * 64 + ((((c2 * 4) ^ ((row & 7) << 4))) >> 2);
    ((unsigned*)WoHi)[u32idx] = (unsigned)h0 | ((unsigned)h1 << 16);
    ((unsigned*)WoLo)[u32idx] = (unsigned)l0 | ((unsigned)l1 << 16);
  }
  __syncthreads();

  short8v woh[4], wol[4];
  const int woswz = (s & 7) << 4;
#pragma unroll
  for (int ks = 0; ks < 4; ++ks) {
    int off = s * 256 + ((ks * 64 + q * 16) ^ woswz);
    woh[ks] = *(const short8v*)((char*)WoHi + off);
    wol[ks] = *(const short8v*)((char*)WoLo + off);
  }
  float bv[8];
#pragma unroll
  for (int nt = 0; nt < 8; ++nt) bv[nt] = B[nt * 16 + s];
  __syncthreads();  // Wo staging area now reusable as hbuf

  const int nchunks = (N + 127) >> 7;
  const int bswz = (s & 7) << 4;

  for (int chunk = bid; chunk < nchunks; chunk += nbk) {
    const int rowbase = chunk * 128 + wave * 32;

    short8v ahi[2][4], alo[2][4];
#pragma unroll
    for (int mt = 0; mt < 2; ++mt) {
      int row = rowbase + mt * 16 + s;
      int crow = row < N ? row : (N - 1);
      const float* xr = X + (size_t)crow * 128;
#pragma unroll
      for (int ks = 0; ks < 4; ++ks) {
        float4 f0 = *(const float4*)(xr + ks * 32 + q * 8);
        float4 f1 = *(const float4*)(xr + ks * 32 + q * 8 + 4);
        float v[8] = {f0.x, f0.y, f0.z, f0.w, f1.x, f1.y, f1.z, f1.w};
        frag_from8(v, ahi[mt][ks], alo[mt][ks]);
      }
    }

    float4v acc[2][8];
#pragma unroll
    for (int mt = 0; mt < 2; ++mt)
#pragma unroll
      for (int nt = 0; nt < 8; ++nt) acc[mt][nt] = (float4v){0.f, 0.f, 0.f, 0.f};

#pragma unroll
    for (int ks = 0; ks < 4; ++ks) {
      short8v bh[8];
#pragma unroll
      for (int nt = 0; nt < 8; ++nt) {
        int c = nt * 16 + s;
        int off = c * 256 + ((ks * 64 + q * 16) ^ bswz);
        bh[nt] = *(const short8v*)((char*)Whi + off);
      }
#pragma unroll
      for (int nt = 0; nt < 8; ++nt) {
#pragma unroll
        for (int mt = 0; mt < 2; ++mt) {
          acc[mt][nt] = __builtin_amdgcn_mfma_f32_16x16x32_bf16(ahi[mt][ks], bh[nt], acc[mt][nt], 0, 0, 0);
          acc[mt][nt] = __builtin_amdgcn_mfma_f32_16x16x32_bf16(alo[mt][ks], bh[nt], acc[mt][nt], 0, 0, 0);
        }
      }
#pragma unroll
      for (int nt = 0; nt < 8; ++nt) {
        int c = nt * 16 + s;
        int off = c * 256 + ((ks * 64 + q * 16) ^ bswz);
        short8v bl = *(const short8v*)((char*)Wlo + off);
#pragma unroll
        for (int mt = 0; mt < 2; ++mt)
          acc[mt][nt] = __builtin_amdgcn_mfma_f32_16x16x32_bf16(ahi[mt][ks], bl, acc[mt][nt], 0, 0, 0);
      }
    }

#pragma unroll
    for (int mt = 0; mt < 2; ++mt) {
      float4v gacc = (float4v){0.f, 0.f, 0.f, 0.f};
#pragma unroll
      for (int ks = 0; ks < 4; ++ks) {
#pragma unroll
        for (int j = 0; j < 2; ++j) {
          int nt = 2 * ks + j;
          int cl = j * 16 + s;
#pragma unroll
          for (int e = 0; e < 4; ++e)
            hbuf[cl * 17 + q * 4 + e] = fmaxf(acc[mt][nt][e] + bv[nt], 0.f);
        }
        float hv[8];
#pragma unroll
        for (int e = 0; e < 8; ++e) hv[e] = hbuf[(q * 8 + e) * 17 + s];
        short8v hh, hl;
        frag_from8(hv, hh, hl);
        gacc = __builtin_amdgcn_mfma_f32_16x16x32_bf16(hh, woh[ks], gacc, 0, 0, 0);
        gacc = __builtin_amdgcn_mfma_f32_16x16x32_bf16(hl, woh[ks], gacc, 0, 0, 0);
        gacc = __builtin_amdgcn_mfma_f32_16x16x32_bf16(hh, wol[ks], gacc, 0, 0, 0);
      }
      int grow = rowbase + mt * 16 + 4 * q;
#pragma unroll
      for (int e = 0; e < 4; ++e)
        if (grow + e < N) G[(size_t)(grow + e) * 16 + s] = gacc[e];
    }
  }
}

// edge space order: [rby (Erby), dby (Edby), rates (Er), dir (Edir)]
// stage A buckets: user=yd, NU+bd  (bins 0..nbinsA) ; stage B: 2*rd, 2*dd+1 (bins 256+)
__device__ __forceinline__ void edge_decode(
    int i, const int* ys, const int* yd, int Erby,
    const int* bs, const int* bd, int Edby,
    const int* rs, const int* rd, int Er,
    const int* ds, const int* dd,
    int NU, int& src, int& bucket, int& bin)
{
  if (i < Erby)            { src = ys[i]; bucket = yd[i];                 bin = bucket >> BIN_SHIFT; }
  else if (i < Erby + Edby){ int j = i - Erby; src = bs[j]; bucket = NU + bd[j]; bin = bucket >> BIN_SHIFT; }
  else if (i < Erby + Edby + Er) { int j = i - Erby - Edby; src = rs[j]; bucket = 2 * rd[j]; bin = 256 + (bucket >> BIN_SHIFT); }
  else                     { int j = i - Erby - Edby - Er; src = ds[j]; bucket = 2 * dd[j] + 1; bin = 256 + (bucket >> BIN_SHIFT); }
}

// ---------------- fixed-capacity binned fill (replaces hist+scan+fill) ---------------
// cursor[512] starts 0; bin window = bin*CAPB; per-(block,bin) reservation atomics.
__global__ __launch_bounds__(256) void fill2_kernel(
    const int* __restrict__ ys, const int* __restrict__ yd, int Erby,
    const int* __restrict__ bs, const int* __restrict__ bd, int Edby,
    const int* __restrict__ rs, const int* __restrict__ rd, int Er,
    const int* __restrict__ ds, const int* __restrict__ dd, int Edir,
    int NU, int* __restrict__ cursor,
    unsigned* __restrict__ binnedA, unsigned* __restrict__ binnedB)
{
  __shared__ int h[512];
  __shared__ int base[512];
  const int E = Erby + Edby + Er + Edir;
  const int c0 = blockIdx.x * 4096;
  const int c1 = (c0 + 4096 < E) ? c0 + 4096 : E;
  h[threadIdx.x] = 0; h[threadIdx.x + 256] = 0;
  __syncthreads();
  for (int i = c0 + threadIdx.x; i < c1; i += 256) {
    int src, bucket, bin;
    edge_decode(i, ys, yd, Erby, bs, bd, Edby, rs, rd, Er, ds, dd, NU, src, bucket, bin);
    atomicAdd(&h[bin], 1);
  }
  __syncthreads();
#pragma unroll
  for (int k = threadIdx.x; k < 512; k += 256) {
    int c = h[k];
    base[k] = c ? atomicAdd(&cursor[k], c) : 0;
    h[k] = 0;
  }
  __syncthreads();
  for (int i = c0 + threadIdx.x; i < c1; i += 256) {
    int src, bucket, bin;
    edge_decode(i, ys, yd, Erby, bs, bd, Edby, rs, rd, Er, ds, dd, NU, src, bucket, bin);
    int r = atomicAdd(&h[bin], 1);
    int pos = base[bin] + r;
    if (pos < CAPB) {
      unsigned code = ((unsigned)src << BIN_SHIFT) | (unsigned)(bucket & (SBIN - 1));
      if (bin < 256) binnedA[(size_t)bin * CAPB + pos] = code;
      else           binnedB[(size_t)(bin - 256) * CAPB + pos] = code;
    }
  }
}

// ---------------- bin scatter in padded windows: exact per-bucket CSR ----------------
// One block per bin; LDS hist[1024]+scan -> bOffs/bCnt for BOTH stages; rerank writes
// ssrc window-locally (L2-aggregated).
__global__ __launch_bounds__(256) void scatter2_kernel(
    const unsigned* __restrict__ binnedA, const unsigned* __restrict__ binnedB,
    const int* __restrict__ cursor, int nbinsA, int HA, int HB,
    int* __restrict__ bOffsA, int* __restrict__ bCntA,
    int* __restrict__ bOffsB, int* __restrict__ bCntB,
    int* __restrict__ ssrcA, int* __restrict__ ssrcB)
{
  __shared__ int cnt[SBIN];
  __shared__ int pref[SBIN];
  __shared__ int wsum[256];
  const int t = threadIdx.x;
  const bool isA = (int)blockIdx.x < nbinsA;
  const int b = isA ? (int)blockIdx.x : (int)blockIdx.x - nbinsA;
  const unsigned* win = (isA ? binnedA : binnedB) + (size_t)b * CAPB;
  int* bOffs = isA ? bOffsA : bOffsB;
  int* bCnt  = isA ? bCntA  : bCntB;
  int* ssrc  = isA ? ssrcA  : ssrcB;
  const int nbuckets = isA ? HA : HB;
  const size_t wbase = (size_t)b * CAPB;
  int n = cursor[isA ? b : 256 + b];
  if (n > CAPB) n = CAPB;

#pragma unroll
  for (int k = t; k < SBIN; k += 256) cnt[k] = 0;
  __syncthreads();
  for (int i = t; i < n; i += 256)
    atomicAdd(&cnt[win[i] & (SBIN - 1)], 1);
  __syncthreads();
  int c0 = cnt[4 * t], c1 = cnt[4 * t + 1], c2 = cnt[4 * t + 2], c3 = cnt[4 * t + 3];
  int s = c0 + c1 + c2 + c3;
  wsum[t] = s;
  __syncthreads();
  for (int d = 1; d < 256; d <<= 1) {
    int add = (t >= d) ? wsum[t - d] : 0;
    __syncthreads();
    wsum[t] += add;
    __syncthreads();
  }
  int base = wsum[t] - s;
  pref[4 * t]     = base;
  pref[4 * t + 1] = base + c0;
  pref[4 * t + 2] = base + c0 + c1;
  pref[4 * t + 3] = base + c0 + c1 + c2;
  __syncthreads();
  const int gb = b << BIN_SHIFT;
#pragma unroll
  for (int k = t; k < SBIN; k += 256) {
    int bucket = gb + k;
    if (bucket < nbuckets) { bOffs[bucket] = (int)(wbase + pref[k]); bCnt[bucket] = cnt[k]; }
  }
  __syncthreads();
#pragma unroll
  for (int k = t; k < SBIN; k += 256) cnt[k] = pref[k];
  __syncthreads();
  for (int i = t; i < n; i += 256) {
    unsigned code = win[i];
    int local = code & (SBIN - 1);
    int r = atomicAdd(&cnt[local], 1);
    ssrc[wbase + r] = (int)(code >> BIN_SHIFT);
  }
}

// ---------------- fused pay gather for users + directors -----------------------------
__global__ __launch_bounds__(256) void gather_pay2_kernel(
    const float* __restrict__ g_m, const float* __restrict__ g_u,
    const float* __restrict__ g_d,
    const int* __restrict__ bOffsA, const int* __restrict__ bCntA,
    const int* __restrict__ ssrcA,
    float* __restrict__ pay_u, float* __restrict__ pay_d, int NU, int ND)
{
  int tid = blockIdx.x * 256 + threadIdx.x;
  int node = tid >> 4, o = tid & 15;
  if (node >= NU + ND) return;
  int start = bOffsA[node], cnt = bCntA[node];
  float sum = 0.f;
  for (int j = 0; j < cnt; ++j) {
    int s = ssrcA[start + j];
    sum += g_m[(size_t)s * 16 + o];
  }
  float mean = 0.5f * sum / fmaxf((float)cnt, 1.f);
  if (node < NU)
    pay_u[(size_t)node * 16 + o] = ALPHA * g_u[(size_t)node * 16 + o] + mean;
  else {
    int nn = node - NU;
    pay_d[(size_t)nn * 16 + o] = ALPHA * g_d[(size_t)nn * 16 + o] + mean;
  }
}

// ---------------- out[m] = b_out + a^2*g_m[m] + mean_rates(pay_u) + mean_dir(pay_d) ---
__global__ __launch_bounds__(256) void final_kernel(
    const float* __restrict__ gm, const float* __restrict__ pay_u,
    const float* __restrict__ pay_d,
    const int* __restrict__ bOffs, const int* __restrict__ bCnt,
    const int* __restrict__ ssrc,
    const float* __restrict__ bo, float* __restrict__ out, int NM)
{
  int tid = blockIdx.x * 256 + threadIdx.x;
  int m = tid >> 4, o = tid & 15;
  if (m >= NM) return;
  int s0 = bOffs[2 * m], c0 = bCnt[2 * m];
  float sr = 0.f;
  for (int j = 0; j < c0; ++j) sr += pay_u[(size_t)ssrc[s0 + j] * 16 + o];
  int s1 = bOffs[2 * m + 1], c1 = bCnt[2 * m + 1];
  float sd = 0.f;
  for (int j = 0; j < c1; ++j) sd += pay_d[(size_t)ssrc[s1 + j] * 16 + o];
  out[(size_t)m * 16 + o] = bo[o] + ALPHA * ALPHA * gm[(size_t)m * 16 + o]
                          + sr / fmaxf((float)c0, 1.f) + sd / fmaxf((float)c1, 1.f);
}

extern "C" void kernel_launch(void* const* d_in, const int* in_sizes, int n_in,
                              void* d_out, int out_size, void* d_ws, size_t ws_size,
                              hipStream_t stream)
{
  const float* x_user  = (const float*)d_in[0];
  const float* x_movie = (const float*)d_in[1];
  const float* x_dir   = (const float*)d_in[2];
  const int* rates_src = (const int*)d_in[3];
  const int* rates_dst = (const int*)d_in[4];
  const int* rby_src   = (const int*)d_in[5];
  const int* rby_dst   = (const int*)d_in[6];
  const int* dir_src   = (const int*)d_in[7];
  const int* dir_dst   = (const int*)d_in[8];
  const int* dby_src   = (const int*)d_in[9];
  const int* dby_dst   = (const int*)d_in[10];
  const float* W_user  = (const float*)d_in[11];
  const float* b_user  = (const float*)d_in[12];
  const float* W_movie = (const float*)d_in[13];
  const float* b_movie = (const float*)d_in[14];
  const float* W_dir   = (const float*)d_in[15];
  const float* b_dir   = (const float*)d_in[16];
  const float* W_out   = (const float*)d_in[17];
  const float* b_out   = (const float*)d_in[18];

  const int NU = in_sizes[0] / 128, NM = in_sizes[1] / 128, ND = in_sizes[2] / 128;
  const int Er = in_sizes[3], Erby = in_sizes[5], Edir = in_sizes[7], Edby = in_sizes[9];

  const int E  = Er + Edir + Erby + Edby;
  const int HA = NU + ND;
  const int HB = 2 * NM;
  const int nbinsA = (HA + SBIN - 1) >> BIN_SHIFT;   // <= 256
  const int nbinsB = (HB + SBIN - 1) >> BIN_SHIFT;   // <= 256

  // ---- workspace layout
  char* w = (char*)d_ws;
  size_t off = 0;
  auto take = [&](size_t bytes) { char* p = w + off; off += (bytes + 255) & ~(size_t)255; return p; };
  float* g_u   = (float*)take((size_t)NU * 16 * 4);
  float* g_m   = (float*)take((size_t)NM * 16 * 4);
  float* g_d   = (float*)take((size_t)ND * 16 * 4);
  float* pay_u = (float*)take((size_t)NU * 16 * 4);
  float* pay_d = (float*)take((size_t)ND * 16 * 4);
  int* cursor     = (int*)take(512 * 4);             // zeroed per-bin counters
  int* bOffsA     = (int*)take((size_t)HA * 4);
  int* bCntA      = (int*)take((size_t)HA * 4);
  int* bOffsB     = (int*)take((size_t)HB * 4);
  int* bCntB      = (int*)take((size_t)HB * 4);
  unsigned* binnedA = (unsigned*)take((size_t)nbinsA * CAPB * 4);
  unsigned* binnedB = (unsigned*)take((size_t)nbinsB * CAPB * 4);
  int* ssrcA      = (int*)take((size_t)nbinsA * CAPB * 4);
  int* ssrcB      = (int*)take((size_t)nbinsB * CAPB * 4);
  if (off > ws_size) return;

  // 1. zero per-bin counters (2 KB)
  hipMemsetAsync(cursor, 0, 512 * 4, stream);

  // 2. fixed-capacity binned fill (no hist/scan pass)
  fill2_kernel<<<(E + 4095) / 4096, 256, 0, stream>>>(
      rby_src, rby_dst, Erby, dby_src, dby_dst, Edby,
      rates_src, rates_dst, Er, dir_src, dir_dst, Edir, NU,
      cursor, binnedA, binnedB);

  // 3. bin scatter in padded windows -> exact per-bucket CSR for both stages
  scatter2_kernel<<<nbinsA + nbinsB, 256, 0, stream>>>(
      binnedA, binnedB, cursor, nbinsA, HA, HB,
      bOffsA, bCntA, bOffsB, bCntB, ssrcA, ssrcB);

  // 4. one MFMA launch for all three ntypes (proportional static partition of 512 blks)
  {
    long long cu = (NU + 127) >> 7, cm = (NM + 127) >> 7, cd = (ND + 127) >> 7;
    long long ct = cu + cm + cd;
    int bu = (int)((512 * cu + ct / 2) / ct);
    int bm = (int)((512 * cm + ct / 2) / ct);
    if (bu < 1) bu = 1;
    if (bm < 1) bm = 1;
    if (bu + bm > 510) { bu = 510 * bu / (bu + bm); bm = 510 - bu; }
    fused_mfma3_kernel<<<512, 256, 0, stream>>>(
        x_user, x_movie, x_dir, W_user, W_movie, W_dir,
        b_user, b_movie, b_dir, W_out, g_u, g_m, g_d,
        NU, NM, ND, bu, bm);
  }

  // 5. fused pay gather (users + directors)
  gather_pay2_kernel<<<((NU + ND) * 16 + 255) / 256, 256, 0, stream>>>(
      g_m, g_u, g_d, bOffsA, bCntA, ssrcA, pay_u, pay_d, NU, ND);

  // 6. out = b_out + a^2*g_m + mean_rates(pay_u) + mean_dir(pay_d)
  final_kernel<<<(NM * 16 + 255) / 256, 256, 0, stream>>>(
      g_m, pay_u, pay_d, bOffsB, bCntB, ssrcB, b_out, (float*)d_out, NM);
}